// Round 1
// baseline (608.375 us; speedup 1.0000x reference)
//
#include <hip/hip_runtime.h>
#include <hip/hip_bf16.h>

#define N_ATOMS 50000
#define DEG 16
#define N_MOL 1000
#define NA 23
#define NB 7
#define O0 32
#define O1 12
#define O2 8
#define OT 52          // 32+12+8
#define YROW (NB*OT)   // 364
#define SROW 108       // 32 + 12*3 + 8*5

// ---------------- K0: zero the output (harness poisons d_out) ----------------
__global__ void k0_zero(float* __restrict__ out) {
    int i = blockIdx.x * 256 + threadIdx.x;
    if (i < N_MOL) out[i] = 0.0f;
}

// ---------------- K1: per-atom y[n][b*52+o] = n1 * sum_a x[n,a]*W1[a,b,o] ----
// Weights live in registers (23 per thread), x broadcast from LDS.
__global__ __launch_bounds__(384) void k1_y(const float* __restrict__ x,
        const float* __restrict__ W1_0, const float* __restrict__ W1_1,
        const float* __restrict__ W1_2, __hip_bfloat16* __restrict__ y) {
    const int ATOMS = 64;
    __shared__ float xt[ATOMS * NA];
    const int t  = threadIdx.x;
    const int n0 = blockIdx.x * ATOMS;
    for (int i = t; i < ATOMS * NA; i += 384) {
        int n = n0 + i / NA;
        xt[i] = (n < N_ATOMS) ? x[(size_t)n0 * NA + i] : 0.0f;
    }
    __syncthreads();
    if (t < YROW) {
        const int b = t / OT;
        const int o = t % OT;
        const float* wp; int stride;
        if (o < O0)            { wp = W1_0 + b * O0 + o;             stride = NB * O0; }
        else if (o < O0 + O1)  { wp = W1_1 + b * O1 + (o - O0);      stride = NB * O1; }
        else                   { wp = W1_2 + b * O2 + (o - O0 - O1); stride = NB * O2; }
        const float n1 = 0.07881104062391006f; // 1/sqrt(23*7)
        float w[NA];
        #pragma unroll
        for (int a = 0; a < NA; a++) w[a] = wp[a * stride] * n1;
        for (int j = 0; j < ATOMS; j++) {
            int n = n0 + j;
            if (n >= N_ATOMS) break;
            float acc = 0.0f;
            #pragma unroll
            for (int a = 0; a < NA; a++) acc += xt[j * NA + a] * w[a];
            y[(size_t)n * YROW + t] = __float2bfloat16(acc);
        }
    }
}

// ---------------- K2: one wave per dst node; 16 edges; build s[n][108] -------
// lane<32: o=lane (m0); lane 32..43: o1=lane-32 (m1, x sh1[0..2]);
// lane 44..51: o2=lane-44 (m2, x sh2[0..4]).
__global__ __launch_bounds__(256) void k2_s(const float* __restrict__ pos,
        const float* __restrict__ edge_attr, const int* __restrict__ edge_src,
        const __hip_bfloat16* __restrict__ y, float* __restrict__ s) {
    const int n    = blockIdx.x * 4 + (threadIdx.x >> 6);
    const int lane = threadIdx.x & 63;
    const float pdx = pos[n * 3 + 0], pdy = pos[n * 3 + 1], pdz = pos[n * 3 + 2];
    int srcs[DEG];
    #pragma unroll
    for (int k = 0; k < DEG; k++) srcs[k] = edge_src[n * DEG + k];
    float a0 = 0.f, a1 = 0.f, a2 = 0.f, a3 = 0.f, a4 = 0.f;
    #pragma unroll
    for (int k = 0; k < DEG; k++) {
        const int src = srcs[k];
        const int e   = n * DEG + k;
        float ea[NB];
        #pragma unroll
        for (int b = 0; b < NB; b++) ea[b] = edge_attr[e * NB + b];
        const float vx = pos[src * 3 + 0] - pdx;
        const float vy = pos[src * 3 + 1] - pdy;
        const float vz = pos[src * 3 + 2] - pdz;
        const float s3 = 1.7320508075688772f, s15 = 3.872983346207417f;
        const float s5h = 1.118033988749895f, s15h = 1.9364916731037085f;
        const float h10 = s3 * vx, h11 = s3 * vy, h12 = s3 * vz;
        const float h20 = s15 * vx * vy, h21 = s15 * vy * vz;
        const float h22 = s5h * (2.f * vz * vz - vx * vx - vy * vy);
        const float h23 = s15 * vx * vz, h24 = s15h * (vx * vx - vy * vy);
        if (lane < OT) {
            const __hip_bfloat16* yr = y + (size_t)src * YROW + lane;
            float m = 0.f;
            #pragma unroll
            for (int b = 0; b < NB; b++) m += ea[b] * __bfloat162float(yr[b * OT]);
            if (lane < O0)            { a0 += m; }
            else if (lane < O0 + O1)  { a0 += m * h10; a1 += m * h11; a2 += m * h12; }
            else                      { a0 += m * h20; a1 += m * h21; a2 += m * h22;
                                        a3 += m * h23; a4 += m * h24; }
        }
    }
    float* sr = s + (size_t)n * SROW;
    const float q = 0.25f; // inv_sqrt_deg, deg==16 always
    if (lane < O0) {
        sr[lane] = a0 * q;
    } else if (lane < O0 + O1) {
        int a = lane - O0;
        sr[32 + a * 3 + 0] = a0 * q; sr[32 + a * 3 + 1] = a1 * q; sr[32 + a * 3 + 2] = a2 * q;
    } else if (lane < OT) {
        int a = lane - (O0 + O1);
        float* p = sr + 68 + a * 5;
        p[0] = a0 * q; p[1] = a1 * q; p[2] = a2 * q; p[3] = a3 * q; p[4] = a4 * q;
    }
}

// ---------------- K3: one wave per dst node; phase-2 + all reductions --------
__global__ __launch_bounds__(256) void k3_out(const float* __restrict__ pos,
        const float* __restrict__ edge_attr, const int* __restrict__ edge_src,
        const float* __restrict__ s,
        const float* __restrict__ W2_0, const float* __restrict__ W2_1,
        const float* __restrict__ W2_2, float* __restrict__ out) {
    const int n    = blockIdx.x * 4 + (threadIdx.x >> 6);
    const int lane = threadIdx.x & 63;
    const float c0 = 0.06681531047810609f;  // 1/sqrt(32*7)
    const float c1 = 0.06299407883487121f;  // 1/(sqrt(12*7)*sqrt(3))
    const float c2 = 0.05976143046671968f;  // 1/(sqrt(8*7)*sqrt(5))
    float w2[NB];
    if (lane < O0) {
        #pragma unroll
        for (int b = 0; b < NB; b++) w2[b] = W2_0[lane * NB + b] * c0;
    } else if (lane < O0 + O1) {
        #pragma unroll
        for (int b = 0; b < NB; b++) w2[b] = W2_1[(lane - O0) * NB + b] * c1;
    } else if (lane < OT) {
        #pragma unroll
        for (int b = 0; b < NB; b++) w2[b] = W2_2[(lane - O0 - O1) * NB + b] * c2;
    } else {
        #pragma unroll
        for (int b = 0; b < NB; b++) w2[b] = 0.f;
    }
    const float pdx = pos[n * 3 + 0], pdy = pos[n * 3 + 1], pdz = pos[n * 3 + 2];
    int srcs[DEG];
    #pragma unroll
    for (int k = 0; k < DEG; k++) srcs[k] = edge_src[n * DEG + k];
    float accum = 0.f;
    #pragma unroll
    for (int k = 0; k < DEG; k++) {
        const int src = srcs[k];
        const int e   = n * DEG + k;
        float ea[NB];
        #pragma unroll
        for (int b = 0; b < NB; b++) ea[b] = edge_attr[e * NB + b];
        float we = 0.f;
        #pragma unroll
        for (int b = 0; b < NB; b++) we += ea[b] * w2[b];
        const float vx = pos[src * 3 + 0] - pdx;
        const float vy = pos[src * 3 + 1] - pdy;
        const float vz = pos[src * 3 + 2] - pdz;
        const float s3 = 1.7320508075688772f, s15 = 3.872983346207417f;
        const float s5h = 1.118033988749895f, s15h = 1.9364916731037085f;
        const float* sr = s + (size_t)src * SROW;
        float p = 0.f;
        if (lane < O0) {
            p = sr[lane];
        } else if (lane < O0 + O1) {
            int a = lane - O0;
            p = sr[32 + a * 3 + 0] * (s3 * vx)
              + sr[32 + a * 3 + 1] * (s3 * vy)
              + sr[32 + a * 3 + 2] * (s3 * vz);
        } else if (lane < OT) {
            int a = lane - (O0 + O1);
            const float h20 = s15 * vx * vy, h21 = s15 * vy * vz;
            const float h22 = s5h * (2.f * vz * vz - vx * vx - vy * vy);
            const float h23 = s15 * vx * vz, h24 = s15h * (vx * vx - vy * vy);
            const float* pp = sr + 68 + a * 5;
            p = pp[0] * h20 + pp[1] * h21 + pp[2] * h22 + pp[3] * h23 + pp[4] * h24;
        }
        accum += p * we;
    }
    #pragma unroll
    for (int off = 32; off >= 1; off >>= 1) accum += __shfl_xor(accum, off, 64);
    if (lane == 0) {
        // node_out*0.25 summed per molecule, / sqrt(50): 0.25/sqrt(50)
        atomicAdd(out + (n / 50), accum * 0.035355339059327376f);
    }
}

extern "C" void kernel_launch(void* const* d_in, const int* in_sizes, int n_in,
                              void* d_out, int out_size, void* d_ws, size_t ws_size,
                              hipStream_t stream) {
    const float* pos  = (const float*)d_in[0];
    const float* x    = (const float*)d_in[1];
    const float* ea   = (const float*)d_in[2];
    const float* W1_0 = (const float*)d_in[3];
    const float* W1_1 = (const float*)d_in[4];
    const float* W1_2 = (const float*)d_in[5];
    const float* W2_0 = (const float*)d_in[6];
    const float* W2_1 = (const float*)d_in[7];
    const float* W2_2 = (const float*)d_in[8];
    const int*   esrc = (const int*)d_in[9];
    // d_in[10] edge_dst, d_in[11] batch: structured (repeat patterns), not needed
    float* out = (float*)d_out;

    __hip_bfloat16* y = (__hip_bfloat16*)d_ws;
    float* s = (float*)((char*)d_ws + (size_t)N_ATOMS * YROW * sizeof(__hip_bfloat16));

    hipLaunchKernelGGL(k0_zero, dim3((N_MOL + 255) / 256), dim3(256), 0, stream, out);
    hipLaunchKernelGGL(k1_y,   dim3((N_ATOMS + 63) / 64), dim3(384), 0, stream,
                       x, W1_0, W1_1, W1_2, y);
    hipLaunchKernelGGL(k2_s,   dim3(N_ATOMS / 4), dim3(256), 0, stream,
                       pos, ea, esrc, y, s);
    hipLaunchKernelGGL(k3_out, dim3(N_ATOMS / 4), dim3(256), 0, stream,
                       pos, ea, esrc, s, W2_0, W2_1, W2_2, out);
}

// Round 2
// 405.029 us; speedup vs baseline: 1.5021x; 1.5021x over previous
//
#include <hip/hip_runtime.h>
#include <hip/hip_bf16.h>

#define N_ATOMS 50000
#define DEG 16
#define N_MOL 1000
#define NA 23
#define NB 7
#define O0 32
#define O1 12
#define O2 8
#define OT 52          // 32+12+8
#define YROW 416       // 52 channels * 8 (7 b-values + 1 pad), bf16
#define SROW 128       // 108 used + pad, bf16

// s-row layout (bf16, index t):
//  [0,32)   : s0[o]            f = 1
//  [32,44)  : s1[a].x          f = sqrt3*vx
//  [44,56)  : s1[a].y          f = sqrt3*vy
//  [56,68)  : s1[a].z          f = sqrt3*vz
//  [68,76)  : s2[a].m0         f = s15*vx*vy
//  [76,84)  : s2[a].m1         f = s15*vy*vz
//  [84,92)  : s2[a].m2         f = s5h*(2zz-xx-yy)
//  [92,100) : s2[a].m3         f = s15*vx*vz
//  [100,108): s2[a].m4         f = s15h*(xx-yy)

__device__ __forceinline__ float bf_lo(unsigned u) { return __uint_as_float(u << 16); }
__device__ __forceinline__ float bf_hi(unsigned u) { return __uint_as_float(u & 0xFFFF0000u); }

// ---------------- K0: zero the output (harness poisons d_out) ----------------
__global__ void k0_zero(float* __restrict__ out) {
    int i = blockIdx.x * 256 + threadIdx.x;
    if (i < N_MOL) out[i] = 0.0f;
}

// ---------------- K1: per-atom y[n][o*8+b] = n1 * sum_a x[n,a]*W1[a,b,o] -----
__global__ __launch_bounds__(384) void k1_y(const float* __restrict__ x,
        const float* __restrict__ W1_0, const float* __restrict__ W1_1,
        const float* __restrict__ W1_2, __hip_bfloat16* __restrict__ y) {
    const int ATOMS = 64;
    __shared__ float xt[ATOMS * NA];
    const int t  = threadIdx.x;
    const int n0 = blockIdx.x * ATOMS;
    for (int i = t; i < ATOMS * NA; i += 384) {
        int n = n0 + i / NA;
        xt[i] = (n < N_ATOMS) ? x[(size_t)n0 * NA + i] : 0.0f;
    }
    __syncthreads();
    if (t < NB * OT) {
        const int b = t % NB;   // coalesced writes: consecutive t -> consecutive b
        const int o = t / NB;
        const float* wp; int stride;
        if (o < O0)            { wp = W1_0 + b * O0 + o;             stride = NB * O0; }
        else if (o < O0 + O1)  { wp = W1_1 + b * O1 + (o - O0);      stride = NB * O1; }
        else                   { wp = W1_2 + b * O2 + (o - O0 - O1); stride = NB * O2; }
        const float n1 = 0.07881104062391006f; // 1/sqrt(23*7)
        float w[NA];
        #pragma unroll
        for (int a = 0; a < NA; a++) w[a] = wp[a * stride] * n1;
        for (int j = 0; j < ATOMS; j++) {
            int n = n0 + j;
            if (n >= N_ATOMS) break;
            float acc = 0.0f;
            #pragma unroll
            for (int a = 0; a < NA; a++) acc += xt[j * NA + a] * w[a];
            y[(size_t)n * YROW + o * 8 + b] = __float2bfloat16(acc);
        }
    }
}

// ---------------- K2: one wave per dst node; single float4 gather per edge ---
__global__ __launch_bounds__(256) void k2_s(const float* __restrict__ pos,
        const float* __restrict__ edge_attr, const int* __restrict__ edge_src,
        const __hip_bfloat16* __restrict__ y, __hip_bfloat16* __restrict__ s2) {
    const int n    = blockIdx.x * 4 + (threadIdx.x >> 6);
    const int lane = threadIdx.x & 63;
    const int ln   = (lane < OT) ? lane : 0;
    const float pdx = pos[n * 3 + 0], pdy = pos[n * 3 + 1], pdz = pos[n * 3 + 2];
    int srcs[DEG];
    #pragma unroll
    for (int k = 0; k < DEG; k++) srcs[k] = edge_src[n * DEG + k];
    float a0 = 0.f, a1 = 0.f, a2 = 0.f, a3 = 0.f, a4 = 0.f;
    #pragma unroll
    for (int k = 0; k < DEG; k++) {
        const int src = srcs[k];
        const int e   = n * DEG + k;
        float ea[NB];
        #pragma unroll
        for (int b = 0; b < NB; b++) ea[b] = edge_attr[e * NB + b];
        // one coalesced 16B load: 8 bf16 = channel ln's 7 b-values (+pad)
        float4 v4 = *(const float4*)(y + (size_t)src * YROW + ln * 8);
        union { float4 f; unsigned u[4]; } U; U.f = v4;
        float yb[7];
        yb[0] = bf_lo(U.u[0]); yb[1] = bf_hi(U.u[0]);
        yb[2] = bf_lo(U.u[1]); yb[3] = bf_hi(U.u[1]);
        yb[4] = bf_lo(U.u[2]); yb[5] = bf_hi(U.u[2]);
        yb[6] = bf_lo(U.u[3]);
        float m = 0.f;
        #pragma unroll
        for (int b = 0; b < NB; b++) m += ea[b] * yb[b];
        const float vx = pos[src * 3 + 0] - pdx;
        const float vy = pos[src * 3 + 1] - pdy;
        const float vz = pos[src * 3 + 2] - pdz;
        const float s3 = 1.7320508075688772f, s15 = 3.872983346207417f;
        const float s5h = 1.118033988749895f, s15h = 1.9364916731037085f;
        const float h10 = s3 * vx, h11 = s3 * vy, h12 = s3 * vz;
        const float h20 = s15 * vx * vy, h21 = s15 * vy * vz;
        const float h22 = s5h * (2.f * vz * vz - vx * vx - vy * vy);
        const float h23 = s15 * vx * vz, h24 = s15h * (vx * vx - vy * vy);
        if (lane < O0)            { a0 += m; }
        else if (lane < O0 + O1)  { a0 += m * h10; a1 += m * h11; a2 += m * h12; }
        else if (lane < OT)       { a0 += m * h20; a1 += m * h21; a2 += m * h22;
                                    a3 += m * h23; a4 += m * h24; }
    }
    __hip_bfloat16* sr = s2 + (size_t)n * SROW;
    const float q = 0.25f; // inv_sqrt_deg, deg==16 always
    if (lane < O0) {
        sr[lane] = __float2bfloat16(a0 * q);
    } else if (lane < O0 + O1) {
        int a = lane - O0;
        sr[32 + a] = __float2bfloat16(a0 * q);
        sr[44 + a] = __float2bfloat16(a1 * q);
        sr[56 + a] = __float2bfloat16(a2 * q);
    } else if (lane < OT) {
        int a = lane - (O0 + O1);
        sr[68  + a] = __float2bfloat16(a0 * q);
        sr[76  + a] = __float2bfloat16(a1 * q);
        sr[84  + a] = __float2bfloat16(a2 * q);
        sr[92  + a] = __float2bfloat16(a3 * q);
        sr[100 + a] = __float2bfloat16(a4 * q);
    }
}

// ---------------- K3: one wave per dst node; single dword gather per edge ----
__global__ __launch_bounds__(256) void k3_out(const float* __restrict__ pos,
        const float* __restrict__ edge_attr, const int* __restrict__ edge_src,
        const __hip_bfloat16* __restrict__ s2,
        const float* __restrict__ W2_0, const float* __restrict__ W2_1,
        const float* __restrict__ W2_2, float* __restrict__ out) {
    const int n    = blockIdx.x * 4 + (threadIdx.x >> 6);
    const int lane = threadIdx.x & 63;
    const float c0 = 0.06681531047810609f;  // 1/sqrt(32*7)
    const float c1 = 0.06299407883487121f;  // 1/(sqrt(12*7)*sqrt(3))
    const float c2 = 0.05976143046671968f;  // 1/(sqrt(8*7)*sqrt(5))
    // per-lane setup: lane j handles s-row elements t0=2j, t1=2j+1
    int code = 0, aA = 0, aB = 0;
    const float* Wb = W2_0; float norm = 0.f;
    const int j = lane;
    if (j < 16)      { code = 0; aA = 2 * j;   aB = aA + 1; Wb = W2_0; norm = c0; }
    else if (j < 34) { int g = (j - 16) / 6, r = (j - 16) % 6;
                       code = 1 + g; aA = 2 * r; aB = aA + 1; Wb = W2_1; norm = c1; }
    else if (j < 54) { int g = (j - 34) / 4, r = (j - 34) % 4;
                       code = 4 + g; aA = 2 * r; aB = aA + 1; Wb = W2_2; norm = c2; }
    float wA[NB], wB[NB];
    #pragma unroll
    for (int b = 0; b < NB; b++) {
        wA[b] = (j < 54) ? Wb[aA * NB + b] * norm : 0.f;
        wB[b] = (j < 54) ? Wb[aB * NB + b] * norm : 0.f;
    }
    // one-hot f selector (9-term fma chain per edge)
    const float fw0 = (code == 0) ? 1.f : 0.f, fw1 = (code == 1) ? 1.f : 0.f;
    const float fw2 = (code == 2) ? 1.f : 0.f, fw3 = (code == 3) ? 1.f : 0.f;
    const float fw4 = (code == 4) ? 1.f : 0.f, fw5 = (code == 5) ? 1.f : 0.f;
    const float fw6 = (code == 6) ? 1.f : 0.f, fw7 = (code == 7) ? 1.f : 0.f;
    const float fw8 = (code == 8) ? 1.f : 0.f;
    const int jj = (j < 54) ? j : 0;

    const float pdx = pos[n * 3 + 0], pdy = pos[n * 3 + 1], pdz = pos[n * 3 + 2];
    int srcs[DEG];
    #pragma unroll
    for (int k = 0; k < DEG; k++) srcs[k] = edge_src[n * DEG + k];
    float accum = 0.f;
    #pragma unroll
    for (int k = 0; k < DEG; k++) {
        const int src = srcs[k];
        const int e   = n * DEG + k;
        // one dword gather: elements t=2j, 2j+1 of s-row
        unsigned u = *(const unsigned*)(s2 + (size_t)src * SROW + 2 * jj);
        float ea[NB];
        #pragma unroll
        for (int b = 0; b < NB; b++) ea[b] = edge_attr[e * NB + b];
        const float vx = pos[src * 3 + 0] - pdx;
        const float vy = pos[src * 3 + 1] - pdy;
        const float vz = pos[src * 3 + 2] - pdz;
        const float s3 = 1.7320508075688772f, s15 = 3.872983346207417f;
        const float s5h = 1.118033988749895f, s15h = 1.9364916731037085f;
        const float h10 = s3 * vx, h11 = s3 * vy, h12 = s3 * vz;
        const float h20 = s15 * vx * vy, h21 = s15 * vy * vz;
        const float h22 = s5h * (2.f * vz * vz - vx * vx - vy * vy);
        const float h23 = s15 * vx * vz, h24 = s15h * (vx * vx - vy * vy);
        const float f = fw0 + fw1 * h10 + fw2 * h11 + fw3 * h12 + fw4 * h20
                      + fw5 * h21 + fw6 * h22 + fw7 * h23 + fw8 * h24;
        float we0 = 0.f, we1 = 0.f;
        #pragma unroll
        for (int b = 0; b < NB; b++) { we0 += ea[b] * wA[b]; we1 += ea[b] * wB[b]; }
        accum += f * (bf_lo(u) * we0 + bf_hi(u) * we1);
    }
    #pragma unroll
    for (int off = 32; off >= 1; off >>= 1) accum += __shfl_xor(accum, off, 64);
    if (lane == 0) {
        // node_out*0.25 summed per molecule, / sqrt(50): 0.25/sqrt(50)
        atomicAdd(out + (n / 50), accum * 0.035355339059327376f);
    }
}

extern "C" void kernel_launch(void* const* d_in, const int* in_sizes, int n_in,
                              void* d_out, int out_size, void* d_ws, size_t ws_size,
                              hipStream_t stream) {
    const float* pos  = (const float*)d_in[0];
    const float* x    = (const float*)d_in[1];
    const float* ea   = (const float*)d_in[2];
    const float* W1_0 = (const float*)d_in[3];
    const float* W1_1 = (const float*)d_in[4];
    const float* W1_2 = (const float*)d_in[5];
    const float* W2_0 = (const float*)d_in[6];
    const float* W2_1 = (const float*)d_in[7];
    const float* W2_2 = (const float*)d_in[8];
    const int*   esrc = (const int*)d_in[9];
    float* out = (float*)d_out;

    __hip_bfloat16* y  = (__hip_bfloat16*)d_ws;
    __hip_bfloat16* s2 = (__hip_bfloat16*)((char*)d_ws
                         + (size_t)N_ATOMS * YROW * sizeof(__hip_bfloat16));

    hipLaunchKernelGGL(k0_zero, dim3((N_MOL + 255) / 256), dim3(256), 0, stream, out);
    hipLaunchKernelGGL(k1_y,   dim3((N_ATOMS + 63) / 64), dim3(384), 0, stream,
                       x, W1_0, W1_1, W1_2, y);
    hipLaunchKernelGGL(k2_s,   dim3(N_ATOMS / 4), dim3(256), 0, stream,
                       pos, ea, esrc, y, s2);
    hipLaunchKernelGGL(k3_out, dim3(N_ATOMS / 4), dim3(256), 0, stream,
                       pos, ea, esrc, s2, W2_0, W2_1, W2_2, out);
}

// Round 3
// 356.966 us; speedup vs baseline: 1.7043x; 1.1346x over previous
//
#include <hip/hip_runtime.h>
#include <hip/hip_bf16.h>

#define N_ATOMS 50000
#define DEG 16
#define N_MOL 1000
#define NA 23
#define NB 7
#define O0 32
#define O1 12
#define O2 8
#define OT 52          // 32+12+8
#define YROW 416       // 52 channels * 8 (7 b-values + 1 pad), bf16
#define SROW 128       // 108 used + pad, bf16

// s-row layout (bf16, index t):
//  [0,32)   : s0[o]            f = 1
//  [32,44)  : s1[a].x          f = sqrt3*vx
//  [44,56)  : s1[a].y          f = sqrt3*vy
//  [56,68)  : s1[a].z          f = sqrt3*vz
//  [68,76)  : s2[a].m0         f = s15*vx*vy
//  [76,84)  : s2[a].m1         f = s15*vy*vz
//  [84,92)  : s2[a].m2         f = s5h*(2zz-xx-yy)
//  [92,100) : s2[a].m3         f = s15*vx*vz
//  [100,108): s2[a].m4         f = s15h*(xx-yy)

__device__ __forceinline__ float bf_lo(unsigned u) { return __uint_as_float(u << 16); }
__device__ __forceinline__ float bf_hi(unsigned u) { return __uint_as_float(u & 0xFFFF0000u); }

// ---------------- K0: zero the output (harness poisons d_out) ----------------
__global__ void k0_zero(float* __restrict__ out) {
    int i = blockIdx.x * 256 + threadIdx.x;
    if (i < N_MOL) out[i] = 0.0f;
}

// ---------------- K1: per-atom y[n][o*8+b] = n1 * sum_a x[n,a]*W1[a,b,o] -----
__global__ __launch_bounds__(384) void k1_y(const float* __restrict__ x,
        const float* __restrict__ W1_0, const float* __restrict__ W1_1,
        const float* __restrict__ W1_2, __hip_bfloat16* __restrict__ y) {
    const int ATOMS = 32;
    __shared__ float xt[ATOMS * NA];
    const int t  = threadIdx.x;
    const int n0 = blockIdx.x * ATOMS;
    for (int i = t; i < ATOMS * NA; i += 384) {
        int n = n0 + i / NA;
        xt[i] = (n < N_ATOMS) ? x[(size_t)n0 * NA + i] : 0.0f;
    }
    __syncthreads();
    if (t < NB * OT) {
        const int b = t % NB;   // coalesced writes: consecutive t -> consecutive b
        const int o = t / NB;
        const float* wp; int stride;
        if (o < O0)            { wp = W1_0 + b * O0 + o;             stride = NB * O0; }
        else if (o < O0 + O1)  { wp = W1_1 + b * O1 + (o - O0);      stride = NB * O1; }
        else                   { wp = W1_2 + b * O2 + (o - O0 - O1); stride = NB * O2; }
        const float n1 = 0.07881104062391006f; // 1/sqrt(23*7)
        float w[NA];
        #pragma unroll
        for (int a = 0; a < NA; a++) w[a] = wp[a * stride] * n1;
        for (int j = 0; j < ATOMS; j++) {
            int n = n0 + j;
            if (n >= N_ATOMS) break;
            float acc = 0.0f;
            #pragma unroll
            for (int a = 0; a < NA; a++) acc += xt[j * NA + a] * w[a];
            y[(size_t)n * YROW + o * 8 + b] = __float2bfloat16(acc);
        }
    }
}

// ---------------- K2: one wave per dst node; single float4 gather per edge ---
// Uniform node index -> scalar loads for edge_src/edge_attr/pos; all 16
// gathers prefetched into VGPRs before use (one vmcnt drain per wave).
__global__ __launch_bounds__(256) void k2_s(const float* __restrict__ pos,
        const float* __restrict__ edge_attr, const int* __restrict__ edge_src,
        const __hip_bfloat16* __restrict__ y, __hip_bfloat16* __restrict__ s2) {
    const int n    = __builtin_amdgcn_readfirstlane(blockIdx.x * 4 + (threadIdx.x >> 6));
    const int lane = threadIdx.x & 63;
    const int ln   = (lane < OT) ? lane : 0;

    int srcs[DEG];
    #pragma unroll
    for (int k = 0; k < DEG; k++)
        srcs[k] = __builtin_amdgcn_readfirstlane(edge_src[n * DEG + k]);

    // prefetch: one coalesced 16B row-chunk per edge (sgpr base + lane voffset)
    float4 g[DEG];
    #pragma unroll
    for (int k = 0; k < DEG; k++) {
        const float4* rowp = (const float4*)(y + (size_t)srcs[k] * YROW);
        g[k] = rowp[ln];
    }

    const float pdx = pos[n * 3 + 0], pdy = pos[n * 3 + 1], pdz = pos[n * 3 + 2];
    float a0 = 0.f, a1 = 0.f, a2 = 0.f, a3 = 0.f, a4 = 0.f;
    #pragma unroll
    for (int k = 0; k < DEG; k++) {
        const int src = srcs[k];
        const int e   = n * DEG + k;
        float ea[NB];
        #pragma unroll
        for (int b = 0; b < NB; b++) ea[b] = edge_attr[e * NB + b];  // scalar loads
        union { float4 f; unsigned u[4]; } U; U.f = g[k];
        float m = ea[0] * bf_lo(U.u[0]) + ea[1] * bf_hi(U.u[0])
                + ea[2] * bf_lo(U.u[1]) + ea[3] * bf_hi(U.u[1])
                + ea[4] * bf_lo(U.u[2]) + ea[5] * bf_hi(U.u[2])
                + ea[6] * bf_lo(U.u[3]);
        const float vx = pos[src * 3 + 0] - pdx;
        const float vy = pos[src * 3 + 1] - pdy;
        const float vz = pos[src * 3 + 2] - pdz;
        const float s3 = 1.7320508075688772f, s15 = 3.872983346207417f;
        const float s5h = 1.118033988749895f, s15h = 1.9364916731037085f;
        const float h10 = s3 * vx, h11 = s3 * vy, h12 = s3 * vz;
        const float h20 = s15 * vx * vy, h21 = s15 * vy * vz;
        const float h22 = s5h * (2.f * vz * vz - vx * vx - vy * vy);
        const float h23 = s15 * vx * vz, h24 = s15h * (vx * vx - vy * vy);
        if (lane < O0)            { a0 += m; }
        else if (lane < O0 + O1)  { a0 += m * h10; a1 += m * h11; a2 += m * h12; }
        else if (lane < OT)       { a0 += m * h20; a1 += m * h21; a2 += m * h22;
                                    a3 += m * h23; a4 += m * h24; }
    }
    __hip_bfloat16* sr = s2 + (size_t)n * SROW;
    const float q = 0.25f; // inv_sqrt_deg, deg==16 always
    if (lane < O0) {
        sr[lane] = __float2bfloat16(a0 * q);
    } else if (lane < O0 + O1) {
        int a = lane - O0;
        sr[32 + a] = __float2bfloat16(a0 * q);
        sr[44 + a] = __float2bfloat16(a1 * q);
        sr[56 + a] = __float2bfloat16(a2 * q);
    } else if (lane < OT) {
        int a = lane - (O0 + O1);
        sr[68  + a] = __float2bfloat16(a0 * q);
        sr[76  + a] = __float2bfloat16(a1 * q);
        sr[84  + a] = __float2bfloat16(a2 * q);
        sr[92  + a] = __float2bfloat16(a3 * q);
        sr[100 + a] = __float2bfloat16(a4 * q);
    }
}

// ---------------- K3: one wave per dst node; single dword gather per edge ----
__global__ __launch_bounds__(256) void k3_out(const float* __restrict__ pos,
        const float* __restrict__ edge_attr, const int* __restrict__ edge_src,
        const __hip_bfloat16* __restrict__ s2,
        const float* __restrict__ W2_0, const float* __restrict__ W2_1,
        const float* __restrict__ W2_2, float* __restrict__ out) {
    const int n    = __builtin_amdgcn_readfirstlane(blockIdx.x * 4 + (threadIdx.x >> 6));
    const int lane = threadIdx.x & 63;
    const float c0 = 0.06681531047810609f;  // 1/sqrt(32*7)
    const float c1 = 0.06299407883487121f;  // 1/(sqrt(12*7)*sqrt(3))
    const float c2 = 0.05976143046671968f;  // 1/(sqrt(8*7)*sqrt(5))
    // per-lane setup: lane j handles s-row elements t0=2j, t1=2j+1
    int code = 0, aA = 0, aB = 0;
    const float* Wb = W2_0; float norm = 0.f;
    const int j = lane;
    if (j < 16)      { code = 0; aA = 2 * j;   aB = aA + 1; Wb = W2_0; norm = c0; }
    else if (j < 34) { int g = (j - 16) / 6, r = (j - 16) % 6;
                       code = 1 + g; aA = 2 * r; aB = aA + 1; Wb = W2_1; norm = c1; }
    else if (j < 54) { int g = (j - 34) / 4, r = (j - 34) % 4;
                       code = 4 + g; aA = 2 * r; aB = aA + 1; Wb = W2_2; norm = c2; }
    float wA[NB], wB[NB];
    #pragma unroll
    for (int b = 0; b < NB; b++) {
        wA[b] = (j < 54) ? Wb[aA * NB + b] * norm : 0.f;
        wB[b] = (j < 54) ? Wb[aB * NB + b] * norm : 0.f;
    }
    const float fw0 = (code == 0) ? 1.f : 0.f, fw1 = (code == 1) ? 1.f : 0.f;
    const float fw2 = (code == 2) ? 1.f : 0.f, fw3 = (code == 3) ? 1.f : 0.f;
    const float fw4 = (code == 4) ? 1.f : 0.f, fw5 = (code == 5) ? 1.f : 0.f;
    const float fw6 = (code == 6) ? 1.f : 0.f, fw7 = (code == 7) ? 1.f : 0.f;
    const float fw8 = (code == 8) ? 1.f : 0.f;
    const int jj = (j < 54) ? j : 0;

    int srcs[DEG];
    #pragma unroll
    for (int k = 0; k < DEG; k++)
        srcs[k] = __builtin_amdgcn_readfirstlane(edge_src[n * DEG + k]);

    // prefetch all 16 gather dwords (sgpr base + constant voffset each)
    unsigned g[DEG];
    #pragma unroll
    for (int k = 0; k < DEG; k++)
        g[k] = *(const unsigned*)(s2 + (size_t)srcs[k] * SROW + 2 * jj);

    const float pdx = pos[n * 3 + 0], pdy = pos[n * 3 + 1], pdz = pos[n * 3 + 2];
    float accum = 0.f;
    #pragma unroll
    for (int k = 0; k < DEG; k++) {
        const int src = srcs[k];
        const int e   = n * DEG + k;
        float ea[NB];
        #pragma unroll
        for (int b = 0; b < NB; b++) ea[b] = edge_attr[e * NB + b];  // scalar loads
        const float vx = pos[src * 3 + 0] - pdx;
        const float vy = pos[src * 3 + 1] - pdy;
        const float vz = pos[src * 3 + 2] - pdz;
        const float s3 = 1.7320508075688772f, s15 = 3.872983346207417f;
        const float s5h = 1.118033988749895f, s15h = 1.9364916731037085f;
        const float h10 = s3 * vx, h11 = s3 * vy, h12 = s3 * vz;
        const float h20 = s15 * vx * vy, h21 = s15 * vy * vz;
        const float h22 = s5h * (2.f * vz * vz - vx * vx - vy * vy);
        const float h23 = s15 * vx * vz, h24 = s15h * (vx * vx - vy * vy);
        const float f = fw0 + fw1 * h10 + fw2 * h11 + fw3 * h12 + fw4 * h20
                      + fw5 * h21 + fw6 * h22 + fw7 * h23 + fw8 * h24;
        float we0 = 0.f, we1 = 0.f;
        #pragma unroll
        for (int b = 0; b < NB; b++) { we0 += ea[b] * wA[b]; we1 += ea[b] * wB[b]; }
        accum += f * (bf_lo(g[k]) * we0 + bf_hi(g[k]) * we1);
    }
    #pragma unroll
    for (int off = 32; off >= 1; off >>= 1) accum += __shfl_xor(accum, off, 64);
    if (lane == 0) {
        // node_out*0.25 summed per molecule, / sqrt(50): 0.25/sqrt(50)
        atomicAdd(out + (n / 50), accum * 0.035355339059327376f);
    }
}

extern "C" void kernel_launch(void* const* d_in, const int* in_sizes, int n_in,
                              void* d_out, int out_size, void* d_ws, size_t ws_size,
                              hipStream_t stream) {
    const float* pos  = (const float*)d_in[0];
    const float* x    = (const float*)d_in[1];
    const float* ea   = (const float*)d_in[2];
    const float* W1_0 = (const float*)d_in[3];
    const float* W1_1 = (const float*)d_in[4];
    const float* W1_2 = (const float*)d_in[5];
    const float* W2_0 = (const float*)d_in[6];
    const float* W2_1 = (const float*)d_in[7];
    const float* W2_2 = (const float*)d_in[8];
    const int*   esrc = (const int*)d_in[9];
    float* out = (float*)d_out;

    __hip_bfloat16* y  = (__hip_bfloat16*)d_ws;
    __hip_bfloat16* s2 = (__hip_bfloat16*)((char*)d_ws
                         + (size_t)N_ATOMS * YROW * sizeof(__hip_bfloat16));

    hipLaunchKernelGGL(k0_zero, dim3((N_MOL + 255) / 256), dim3(256), 0, stream, out);
    hipLaunchKernelGGL(k1_y,   dim3((N_ATOMS + 31) / 32), dim3(384), 0, stream,
                       x, W1_0, W1_1, W1_2, y);
    hipLaunchKernelGGL(k2_s,   dim3(N_ATOMS / 4), dim3(256), 0, stream,
                       pos, ea, esrc, y, s2);
    hipLaunchKernelGGL(k3_out, dim3(N_ATOMS / 4), dim3(256), 0, stream,
                       pos, ea, esrc, s2, W2_0, W2_1, W2_2, out);
}

// Round 4
// 286.969 us; speedup vs baseline: 2.1200x; 1.2439x over previous
//
#include <hip/hip_runtime.h>
#include <hip/hip_bf16.h>

#define N_ATOMS 50000
#define DEG 16
#define N_MOL 1000
#define NA 23
#define NB 7
#define O0 32
#define O1 12
#define O2 8
#define OT 52          // 32+12+8
#define SROW 128       // s-row: 108 used + pad, bf16 (raw ushort bits)
#define KPAD 224       // MFMA K dim: k = b*32 + a (b=0..6, a=0..22 valid)
#define OPAD 64        // MFMA N dim: 4 tiles of 16 (o=52..63 zero)
#define NPW 8          // nodes per wave in k2

// s-row layout (bf16 bits, index t):
//  [0,32)   s0[o]        [32,44) s1.x   [44,56) s1.y   [56,68) s1.z
//  [68,76)  s2.m0  [76,84) s2.m1  [84,92) s2.m2  [92,100) s2.m3  [100,108) s2.m4

typedef __attribute__((ext_vector_type(8))) short short8;
typedef __attribute__((ext_vector_type(4))) float floatx4;

__device__ __forceinline__ unsigned short bfbits(float f) {  // f32 -> bf16 RNE
    unsigned u = __float_as_uint(f);
    u += 0x7FFFu + ((u >> 16) & 1u);
    return (unsigned short)(u >> 16);
}
__device__ __forceinline__ float bf_lo(unsigned u) { return __uint_as_float(u << 16); }
__device__ __forceinline__ float bf_hi(unsigned u) { return __uint_as_float(u & 0xFFFF0000u); }
__device__ __forceinline__ float wred4(float v) {  // sum over the 4 quads
    v += __shfl_xor(v, 16, 64); v += __shfl_xor(v, 32, 64); return v;
}

// ---------------- K0: zero the output ----------------------------------------
__global__ void k0_zero(float* __restrict__ out) {
    int i = blockIdx.x * 256 + threadIdx.x;
    if (i < N_MOL) out[i] = 0.0f;
}

// ---------------- K1w: reformat W1 -> Wt[col=o(64)][k=b*32+a (224)] bf16 -----
__global__ void k1_w(const float* __restrict__ W1_0, const float* __restrict__ W1_1,
                     const float* __restrict__ W1_2, unsigned short* __restrict__ Wt) {
    int idx = blockIdx.x * 256 + threadIdx.x;
    if (idx >= OPAD * KPAD) return;
    int col = idx / KPAD, k = idx % KPAD;
    int b = k >> 5, a = k & 31;
    float val = 0.f;
    if (a < NA && col < OT) {
        const float n1 = 0.07881104062391006f; // 1/sqrt(23*7)
        if (col < O0)           val = W1_0[(a * NB + b) * O0 + col] * n1;
        else if (col < O0 + O1) val = W1_1[(a * NB + b) * O1 + (col - O0)] * n1;
        else                    val = W1_2[(a * NB + b) * O2 + (col - O0 - O1)] * n1;
    }
    Wt[idx] = bfbits(val);
}

// ---------------- K2: per-node MFMA GEMM, x gathered directly ----------------
// One wave handles NPW nodes. M=16 edges, K=224 (7 steps of 32), N=64 (4 tiles).
// A[m=lane&15][k=quad*8+j] built in-register: t = x[src(e)][a] * ea[e][b],
// e = lane&15, b = kstep, a = quad*8+j. B frags register-resident (28 x 16B).
// D: row(m=edge) = quad*4+reg, col(o) = lane&15.
__global__ __launch_bounds__(256, 2) void k2_s(const float* __restrict__ pos,
        const float* __restrict__ x, const float* __restrict__ edge_attr,
        const int* __restrict__ edge_src, const unsigned short* __restrict__ Wt,
        unsigned short* __restrict__ s2) {
    __shared__ float hbuf[4][16][8];
    const int tid  = threadIdx.x;
    const int wid  = tid >> 6;
    const int lane = tid & 63;
    const int lcol = lane & 15;
    const int quad = lane >> 4;
    const int wgid = __builtin_amdgcn_readfirstlane(blockIdx.x * 4 + wid);
    if (wgid * NPW >= N_ATOMS) return;

    // B fragments once per wave (Wt is ~28.7 KB, L2-hot)
    short8 bf[7][4];
    #pragma unroll
    for (int s = 0; s < 7; s++)
        #pragma unroll
        for (int t = 0; t < 4; t++) {
            union { uint4 u; short8 v; } U;
            U.u = *(const uint4*)(Wt + (t * 16 + lcol) * KPAD + s * 32 + quad * 8);
            bf[s][t] = U.v;
        }

    float (*hb)[8] = hbuf[wid];
    const float s3 = 1.7320508075688772f, s15 = 3.872983346207417f;
    const float s5h = 1.118033988749895f, s15h = 1.9364916731037085f;

    #pragma unroll 1
    for (int i = 0; i < NPW; i++) {
        const int n = __builtin_amdgcn_readfirstlane(wgid * NPW + i);
        if (n >= N_ATOMS) break;
        // per-lane edge e = lcol
        const int src_v = edge_src[n * DEG + lcol];
        float ea[NB];
        const float* eap = edge_attr + ((size_t)n * DEG + lcol) * NB;
        #pragma unroll
        for (int b = 0; b < NB; b++) ea[b] = eap[b];
        float xv[8];
        #pragma unroll
        for (int j = 0; j < 8; j++) {
            int a = quad * 8 + j;
            xv[j] = (a < NA) ? x[src_v * NA + a] : 0.f;
        }
        // sh factors for all 16 edges (lanes 0..15), staged in LDS
        const float pdx = pos[n * 3 + 0], pdy = pos[n * 3 + 1], pdz = pos[n * 3 + 2];
        if (lane < 16) {
            const float vx = pos[src_v * 3 + 0] - pdx;
            const float vy = pos[src_v * 3 + 1] - pdy;
            const float vz = pos[src_v * 3 + 2] - pdz;
            hb[lane][0] = s3 * vx;  hb[lane][1] = s3 * vy;  hb[lane][2] = s3 * vz;
            hb[lane][3] = s15 * vx * vy;
            hb[lane][4] = s15 * vy * vz;
            hb[lane][5] = s5h * (2.f * vz * vz - vx * vx - vy * vy);
            hb[lane][6] = s15 * vx * vz;
            hb[lane][7] = s15h * (vx * vx - vy * vy);
        }
        // MFMA: 7 K-steps x 4 N-tiles
        floatx4 acc0 = {0.f,0.f,0.f,0.f}, acc1 = {0.f,0.f,0.f,0.f};
        floatx4 acc2 = {0.f,0.f,0.f,0.f}, acc3 = {0.f,0.f,0.f,0.f};
        #pragma unroll
        for (int s = 0; s < 7; s++) {
            const float eb = ea[s];
            short8 af;
            #pragma unroll
            for (int j = 0; j < 8; j++) af[j] = (short)bfbits(xv[j] * eb);
            acc0 = __builtin_amdgcn_mfma_f32_16x16x32_bf16(af, bf[s][0], acc0, 0, 0, 0);
            acc1 = __builtin_amdgcn_mfma_f32_16x16x32_bf16(af, bf[s][1], acc1, 0, 0, 0);
            acc2 = __builtin_amdgcn_mfma_f32_16x16x32_bf16(af, bf[s][2], acc2, 0, 0, 0);
            acc3 = __builtin_amdgcn_mfma_f32_16x16x32_bf16(af, bf[s][3], acc3, 0, 0, 0);
        }
        // epilogue: this lane's 4 D-edges are e = quad*4+r
        float4 hA[4], hB[4];
        #pragma unroll
        for (int r = 0; r < 4; r++) {
            int e = quad * 4 + r;
            hA[r] = *(const float4*)&hb[e][0];   // h1x,h1y,h1z,h2m0
            hB[r] = *(const float4*)&hb[e][4];   // h2m1..h2m4
        }
        const float q = 0.25f; // inv_sqrt_deg
        unsigned short* sr = s2 + (size_t)n * SROW;
        float v0 = wred4(acc0[0] + acc0[1] + acc0[2] + acc0[3]);
        float v1 = wred4(acc1[0] + acc1[1] + acc1[2] + acc1[3]);
        if (quad == 0) { sr[lcol] = bfbits(v0 * q); sr[16 + lcol] = bfbits(v1 * q); }
        if (lcol < 12) {  // s1[a=lcol] from acc2
            float p0 = 0.f, p1 = 0.f, p2 = 0.f;
            #pragma unroll
            for (int r = 0; r < 4; r++) {
                float m = acc2[r];
                p0 += m * hA[r].x; p1 += m * hA[r].y; p2 += m * hA[r].z;
            }
            p0 = wred4(p0); p1 = wred4(p1); p2 = wred4(p2);
            if (quad == 0) {
                sr[32 + lcol] = bfbits(p0 * q);
                sr[44 + lcol] = bfbits(p1 * q);
                sr[56 + lcol] = bfbits(p2 * q);
            }
        } else {          // s2[a=lcol-12] from acc2
            int a = lcol - 12;
            float p0 = 0.f, p1 = 0.f, p2 = 0.f, p3 = 0.f, p4 = 0.f;
            #pragma unroll
            for (int r = 0; r < 4; r++) {
                float m = acc2[r];
                p0 += m * hA[r].w; p1 += m * hB[r].x; p2 += m * hB[r].y;
                p3 += m * hB[r].z; p4 += m * hB[r].w;
            }
            p0 = wred4(p0); p1 = wred4(p1); p2 = wred4(p2); p3 = wred4(p3); p4 = wred4(p4);
            if (quad == 0) {
                sr[68 + a] = bfbits(p0 * q); sr[76 + a] = bfbits(p1 * q);
                sr[84 + a] = bfbits(p2 * q); sr[92 + a] = bfbits(p3 * q);
                sr[100 + a] = bfbits(p4 * q);
            }
        }
        if (lcol < 4) {   // s2[a=lcol+4] from acc3
            int a = lcol + 4;
            float p0 = 0.f, p1 = 0.f, p2 = 0.f, p3 = 0.f, p4 = 0.f;
            #pragma unroll
            for (int r = 0; r < 4; r++) {
                float m = acc3[r];
                p0 += m * hA[r].w; p1 += m * hB[r].x; p2 += m * hB[r].y;
                p3 += m * hB[r].z; p4 += m * hB[r].w;
            }
            p0 = wred4(p0); p1 = wred4(p1); p2 = wred4(p2); p3 = wred4(p3); p4 = wred4(p4);
            if (quad == 0) {
                sr[68 + a] = bfbits(p0 * q); sr[76 + a] = bfbits(p1 * q);
                sr[84 + a] = bfbits(p2 * q); sr[92 + a] = bfbits(p3 * q);
                sr[100 + a] = bfbits(p4 * q);
            }
        }
    }
}

// ---------------- K3: one wave per dst node; single dword gather per edge ----
__global__ __launch_bounds__(256) void k3_out(const float* __restrict__ pos,
        const float* __restrict__ edge_attr, const int* __restrict__ edge_src,
        const unsigned short* __restrict__ s2,
        const float* __restrict__ W2_0, const float* __restrict__ W2_1,
        const float* __restrict__ W2_2, float* __restrict__ out) {
    const int n    = __builtin_amdgcn_readfirstlane(blockIdx.x * 4 + (threadIdx.x >> 6));
    const int lane = threadIdx.x & 63;
    const float c0 = 0.06681531047810609f;  // 1/sqrt(32*7)
    const float c1 = 0.06299407883487121f;  // 1/(sqrt(12*7)*sqrt(3))
    const float c2 = 0.05976143046671968f;  // 1/(sqrt(8*7)*sqrt(5))
    int code = 0, aA = 0, aB = 0;
    const float* Wb = W2_0; float norm = 0.f;
    const int j = lane;
    if (j < 16)      { code = 0; aA = 2 * j;   aB = aA + 1; Wb = W2_0; norm = c0; }
    else if (j < 34) { int g = (j - 16) / 6, r = (j - 16) % 6;
                       code = 1 + g; aA = 2 * r; aB = aA + 1; Wb = W2_1; norm = c1; }
    else if (j < 54) { int g = (j - 34) / 4, r = (j - 34) % 4;
                       code = 4 + g; aA = 2 * r; aB = aA + 1; Wb = W2_2; norm = c2; }
    float wA[NB], wB[NB];
    #pragma unroll
    for (int b = 0; b < NB; b++) {
        wA[b] = (j < 54) ? Wb[aA * NB + b] * norm : 0.f;
        wB[b] = (j < 54) ? Wb[aB * NB + b] * norm : 0.f;
    }
    const float fw0 = (code == 0) ? 1.f : 0.f, fw1 = (code == 1) ? 1.f : 0.f;
    const float fw2 = (code == 2) ? 1.f : 0.f, fw3 = (code == 3) ? 1.f : 0.f;
    const float fw4 = (code == 4) ? 1.f : 0.f, fw5 = (code == 5) ? 1.f : 0.f;
    const float fw6 = (code == 6) ? 1.f : 0.f, fw7 = (code == 7) ? 1.f : 0.f;
    const float fw8 = (code == 8) ? 1.f : 0.f;
    const int jj = (j < 54) ? j : 0;

    int srcs[DEG];
    #pragma unroll
    for (int k = 0; k < DEG; k++)
        srcs[k] = __builtin_amdgcn_readfirstlane(edge_src[n * DEG + k]);

    unsigned g[DEG];
    #pragma unroll
    for (int k = 0; k < DEG; k++)
        g[k] = *(const unsigned*)(s2 + (size_t)srcs[k] * SROW + 2 * jj);

    const float pdx = pos[n * 3 + 0], pdy = pos[n * 3 + 1], pdz = pos[n * 3 + 2];
    float accum = 0.f;
    #pragma unroll
    for (int k = 0; k < DEG; k++) {
        const int src = srcs[k];
        const int e   = n * DEG + k;
        float ea[NB];
        #pragma unroll
        for (int b = 0; b < NB; b++) ea[b] = edge_attr[e * NB + b];  // scalar loads
        const float vx = pos[src * 3 + 0] - pdx;
        const float vy = pos[src * 3 + 1] - pdy;
        const float vz = pos[src * 3 + 2] - pdz;
        const float s3 = 1.7320508075688772f, s15 = 3.872983346207417f;
        const float s5h = 1.118033988749895f, s15h = 1.9364916731037085f;
        const float h10 = s3 * vx, h11 = s3 * vy, h12 = s3 * vz;
        const float h20 = s15 * vx * vy, h21 = s15 * vy * vz;
        const float h22 = s5h * (2.f * vz * vz - vx * vx - vy * vy);
        const float h23 = s15 * vx * vz, h24 = s15h * (vx * vx - vy * vy);
        const float f = fw0 + fw1 * h10 + fw2 * h11 + fw3 * h12 + fw4 * h20
                      + fw5 * h21 + fw6 * h22 + fw7 * h23 + fw8 * h24;
        float we0 = 0.f, we1 = 0.f;
        #pragma unroll
        for (int b = 0; b < NB; b++) { we0 += ea[b] * wA[b]; we1 += ea[b] * wB[b]; }
        accum += f * (bf_lo(g[k]) * we0 + bf_hi(g[k]) * we1);
    }
    #pragma unroll
    for (int off = 32; off >= 1; off >>= 1) accum += __shfl_xor(accum, off, 64);
    if (lane == 0) {
        atomicAdd(out + (n / 50), accum * 0.035355339059327376f); // 0.25/sqrt(50)
    }
}

extern "C" void kernel_launch(void* const* d_in, const int* in_sizes, int n_in,
                              void* d_out, int out_size, void* d_ws, size_t ws_size,
                              hipStream_t stream) {
    const float* pos  = (const float*)d_in[0];
    const float* x    = (const float*)d_in[1];
    const float* ea   = (const float*)d_in[2];
    const float* W1_0 = (const float*)d_in[3];
    const float* W1_1 = (const float*)d_in[4];
    const float* W1_2 = (const float*)d_in[5];
    const float* W2_0 = (const float*)d_in[6];
    const float* W2_1 = (const float*)d_in[7];
    const float* W2_2 = (const float*)d_in[8];
    const int*   esrc = (const int*)d_in[9];
    float* out = (float*)d_out;

    unsigned short* Wt = (unsigned short*)d_ws;                       // 64*224*2 = 28672 B
    unsigned short* s2 = (unsigned short*)((char*)d_ws + 32768);      // 50000*128*2 = 12.8 MB

    hipLaunchKernelGGL(k0_zero, dim3(4), dim3(256), 0, stream, out);
    hipLaunchKernelGGL(k1_w, dim3((OPAD * KPAD + 255) / 256), dim3(256), 0, stream,
                       W1_0, W1_1, W1_2, Wt);
    hipLaunchKernelGGL(k2_s, dim3((N_ATOMS / NPW + 3) / 4), dim3(256), 0, stream,
                       pos, x, ea, esrc, Wt, s2);
    hipLaunchKernelGGL(k3_out, dim3(N_ATOMS / 4), dim3(256), 0, stream,
                       pos, ea, esrc, s2, W2_0, W2_1, W2_2, out);
}

// Round 5
// 253.902 us; speedup vs baseline: 2.3961x; 1.1302x over previous
//
#include <hip/hip_runtime.h>
#include <hip/hip_bf16.h>

#define N_ATOMS 50000
#define DEG 16
#define N_MOL 1000
#define NA 23
#define NB 7
#define O0 32
#define O1 12
#define O2 8
#define OT 52          // 32+12+8
#define SROW 128       // s-row: 108 used + pad, bf16 (raw ushort bits)
#define NPW 8          // nodes per wave in k2
#define WFRAG_N 1792   // 28 fragments * 64 lanes, short8 each (28672 B)

// s-row layout (bf16 bits, index t):
//  [0,32)   s0[o]        [32,44) s1.x   [44,56) s1.y   [56,68) s1.z
//  [68,76)  s2.m0  [76,84) s2.m1  [84,92) s2.m2  [92,100) s2.m3  [100,108) s2.m4

typedef __attribute__((ext_vector_type(8))) short short8;
typedef __attribute__((ext_vector_type(4))) float floatx4;

__device__ __forceinline__ unsigned short bfbits(float f) {  // f32 -> bf16 RNE
    unsigned u = __float_as_uint(f);
    u += 0x7FFFu + ((u >> 16) & 1u);
    return (unsigned short)(u >> 16);
}
__device__ __forceinline__ float bf_lo(unsigned u) { return __uint_as_float(u << 16); }
__device__ __forceinline__ float bf_hi(unsigned u) { return __uint_as_float(u & 0xFFFF0000u); }
__device__ __forceinline__ float wred4(float v) {  // sum over the 4 quads
    v += __shfl_xor(v, 16, 64); v += __shfl_xor(v, 32, 64); return v;
}

// ---------------- K0: zero the output ----------------------------------------
__global__ void k0_zero(float* __restrict__ out) {
    int i = blockIdx.x * 256 + threadIdx.x;
    if (i < N_MOL) out[i] = 0.0f;
}

// ---------------- K1w: W1 -> fragment-ordered table --------------------------
// Wfrag element idx = ((s*4+t)*64 + lane)*8 + j holds bf16 of
//   n1 * W1[k = s*32 + (lane>>4)*8 + j][o = t*16 + (lane&15)]   (0 if padded)
__global__ void k1_w(const float* __restrict__ W1_0, const float* __restrict__ W1_1,
                     const float* __restrict__ W1_2, unsigned short* __restrict__ Wfrag) {
    int idx = blockIdx.x * 256 + threadIdx.x;
    if (idx >= WFRAG_N * 8) return;
    int j    = idx & 7;
    int lane = (idx >> 3) & 63;
    int st   = idx >> 9;           // 0..27
    int s = st >> 2, t = st & 3;
    int q = lane >> 4, c = lane & 15;
    int b = s, a = q * 8 + j, o = t * 16 + c;
    float val = 0.f;
    if (a < NA && o < OT) {
        const float n1 = 0.07881104062391006f; // 1/sqrt(23*7)
        if (o < O0)           val = W1_0[(a * NB + b) * O0 + o] * n1;
        else if (o < O0 + O1) val = W1_1[(a * NB + b) * O1 + (o - O0)] * n1;
        else                  val = W1_2[(a * NB + b) * O2 + (o - O0 - O1)] * n1;
    }
    Wfrag[idx] = bfbits(val);
}

// ---------------- K2: per-node MFMA GEMM, x gathered, B-frags in LDS ---------
__global__ __launch_bounds__(256, 3) void k2_s(const float* __restrict__ pos,
        const float* __restrict__ x, const float* __restrict__ edge_attr,
        const int* __restrict__ edge_src, const unsigned short* __restrict__ Wfrag,
        unsigned short* __restrict__ sbuf) {
    __shared__ short8 wfrag[WFRAG_N];          // 28672 B, shared by 4 waves
    __shared__ float hbuf[4][16][8];
    const int tid  = threadIdx.x;
    const int wid  = tid >> 6;
    const int lane = tid & 63;
    const int lcol = lane & 15;
    const int quad = lane >> 4;

    {   // cooperative stage of the weight fragments
        uint4* dst = (uint4*)wfrag;
        const uint4* src4 = (const uint4*)Wfrag;
        for (int i = tid; i < WFRAG_N; i += 256) dst[i] = src4[i];
    }
    __syncthreads();

    const int wgid = __builtin_amdgcn_readfirstlane(blockIdx.x * 4 + wid);
    const int base = wgid * NPW;
    if (base >= N_ATOMS) return;

    float (*hb)[8] = hbuf[wid];
    const float s3 = 1.7320508075688772f, s15 = 3.872983346207417f;
    const float s5h = 1.118033988749895f, s15h = 1.9364916731037085f;

    // -- software pipeline: edge_src 2 deep, x/ea 1 deep --
    auto clampn = [&](int i) { int nn = base + i; return nn < N_ATOMS ? nn : N_ATOMS - 1; };
    int s0v = edge_src[clampn(0) * DEG + lcol];
    int s1v = edge_src[clampn(1) * DEG + lcol];
    float x0[8], e0v[NB];
    #pragma unroll
    for (int j = 0; j < 8; j++) { int a = quad * 8 + j; x0[j] = (a < NA) ? x[s0v * NA + a] : 0.f; }
    {
        const float* p = edge_attr + ((size_t)clampn(0) * DEG + lcol) * NB;
        #pragma unroll
        for (int b = 0; b < NB; b++) e0v[b] = p[b];
    }

    #pragma unroll 1
    for (int i = 0; i < NPW; i++) {
        const int n = base + i;
        if (n >= N_ATOMS) break;
        // prefetch next stage
        int s2v = edge_src[clampn(i + 2 < NPW ? i + 2 : i) * DEG + lcol];
        float x1[8], e1v[NB];
        #pragma unroll
        for (int j = 0; j < 8; j++) { int a = quad * 8 + j; x1[j] = (a < NA) ? x[s1v * NA + a] : 0.f; }
        {
            const float* p = edge_attr + ((size_t)clampn(i + 1 < NPW ? i + 1 : i) * DEG + lcol) * NB;
            #pragma unroll
            for (int b = 0; b < NB; b++) e1v[b] = p[b];
        }
        // h factors for this node (lane e = lcol, lanes 0..15)
        const float pdx = pos[n * 3 + 0], pdy = pos[n * 3 + 1], pdz = pos[n * 3 + 2];
        if (lane < 16) {
            const float vx = pos[s0v * 3 + 0] - pdx;
            const float vy = pos[s0v * 3 + 1] - pdy;
            const float vz = pos[s0v * 3 + 2] - pdz;
            hb[lane][0] = s3 * vx;  hb[lane][1] = s3 * vy;  hb[lane][2] = s3 * vz;
            hb[lane][3] = s15 * vx * vy;
            hb[lane][4] = s15 * vy * vz;
            hb[lane][5] = s5h * (2.f * vz * vz - vx * vx - vy * vy);
            hb[lane][6] = s15 * vx * vz;
            hb[lane][7] = s15h * (vx * vx - vy * vy);
        }
        // MFMA: 7 K-steps x 4 N-tiles, B-frags streamed from LDS
        floatx4 acc0 = {0.f,0.f,0.f,0.f}, acc1 = {0.f,0.f,0.f,0.f};
        floatx4 acc2 = {0.f,0.f,0.f,0.f}, acc3 = {0.f,0.f,0.f,0.f};
        #pragma unroll
        for (int s = 0; s < 7; s++) {
            const float eb = e0v[s];
            union { short8 v; unsigned u[4]; } af;
            #pragma unroll
            for (int j = 0; j < 8; j += 2) {
                float2 pr; pr.x = x0[j] * eb; pr.y = x0[j + 1] * eb;
                __hip_bfloat162 bb = __float22bfloat162_rn(pr);
                af.u[j >> 1] = *(unsigned*)&bb;
            }
            acc0 = __builtin_amdgcn_mfma_f32_16x16x32_bf16(af.v, wfrag[(s*4+0)*64 + lane], acc0, 0, 0, 0);
            acc1 = __builtin_amdgcn_mfma_f32_16x16x32_bf16(af.v, wfrag[(s*4+1)*64 + lane], acc1, 0, 0, 0);
            acc2 = __builtin_amdgcn_mfma_f32_16x16x32_bf16(af.v, wfrag[(s*4+2)*64 + lane], acc2, 0, 0, 0);
            acc3 = __builtin_amdgcn_mfma_f32_16x16x32_bf16(af.v, wfrag[(s*4+3)*64 + lane], acc3, 0, 0, 0);
        }
        // epilogue (verified in round 4): this lane's 4 D-edges are e = quad*4+r
        float4 hA[4], hB[4];
        #pragma unroll
        for (int r = 0; r < 4; r++) {
            int e = quad * 4 + r;
            hA[r] = *(const float4*)&hb[e][0];   // h1x,h1y,h1z,h2m0
            hB[r] = *(const float4*)&hb[e][4];   // h2m1..h2m4
        }
        const float q = 0.25f; // inv_sqrt_deg
        unsigned short* sr = sbuf + (size_t)n * SROW;
        float v0 = wred4(acc0[0] + acc0[1] + acc0[2] + acc0[3]);
        float v1 = wred4(acc1[0] + acc1[1] + acc1[2] + acc1[3]);
        if (quad == 0) { sr[lcol] = bfbits(v0 * q); sr[16 + lcol] = bfbits(v1 * q); }
        if (lcol < 12) {  // s1[a=lcol] from acc2
            float p0 = 0.f, p1 = 0.f, p2 = 0.f;
            #pragma unroll
            for (int r = 0; r < 4; r++) {
                float m = acc2[r];
                p0 += m * hA[r].x; p1 += m * hA[r].y; p2 += m * hA[r].z;
            }
            p0 = wred4(p0); p1 = wred4(p1); p2 = wred4(p2);
            if (quad == 0) {
                sr[32 + lcol] = bfbits(p0 * q);
                sr[44 + lcol] = bfbits(p1 * q);
                sr[56 + lcol] = bfbits(p2 * q);
            }
        } else {          // s2[a=lcol-12] from acc2
            int a = lcol - 12;
            float p0 = 0.f, p1 = 0.f, p2 = 0.f, p3 = 0.f, p4 = 0.f;
            #pragma unroll
            for (int r = 0; r < 4; r++) {
                float m = acc2[r];
                p0 += m * hA[r].w; p1 += m * hB[r].x; p2 += m * hB[r].y;
                p3 += m * hB[r].z; p4 += m * hB[r].w;
            }
            p0 = wred4(p0); p1 = wred4(p1); p2 = wred4(p2); p3 = wred4(p3); p4 = wred4(p4);
            if (quad == 0) {
                sr[68 + a] = bfbits(p0 * q); sr[76 + a] = bfbits(p1 * q);
                sr[84 + a] = bfbits(p2 * q); sr[92 + a] = bfbits(p3 * q);
                sr[100 + a] = bfbits(p4 * q);
            }
        }
        if (lcol < 4) {   // s2[a=lcol+4] from acc3
            int a = lcol + 4;
            float p0 = 0.f, p1 = 0.f, p2 = 0.f, p3 = 0.f, p4 = 0.f;
            #pragma unroll
            for (int r = 0; r < 4; r++) {
                float m = acc3[r];
                p0 += m * hA[r].w; p1 += m * hB[r].x; p2 += m * hB[r].y;
                p3 += m * hB[r].z; p4 += m * hB[r].w;
            }
            p0 = wred4(p0); p1 = wred4(p1); p2 = wred4(p2); p3 = wred4(p3); p4 = wred4(p4);
            if (quad == 0) {
                sr[68 + a] = bfbits(p0 * q); sr[76 + a] = bfbits(p1 * q);
                sr[84 + a] = bfbits(p2 * q); sr[92 + a] = bfbits(p3 * q);
                sr[100 + a] = bfbits(p4 * q);
            }
        }
        // rotate pipeline registers
        s0v = s1v; s1v = s2v;
        #pragma unroll
        for (int j = 0; j < 8; j++) x0[j] = x1[j];
        #pragma unroll
        for (int b = 0; b < NB; b++) e0v[b] = e1v[b];
    }
}

// ---------------- K3: one wave per dst node; LDS h-table, 1 dword gather -----
__global__ __launch_bounds__(256) void k3_out(const float* __restrict__ pos,
        const float* __restrict__ edge_attr, const int* __restrict__ edge_src,
        const unsigned short* __restrict__ sbuf,
        const float* __restrict__ W2_0, const float* __restrict__ W2_1,
        const float* __restrict__ W2_2, float* __restrict__ out) {
    __shared__ float hb[4][9][16];   // [wave][code][edge]; row 0 = 1.0
    const int tid  = threadIdx.x;
    const int wid  = tid >> 6;
    const int lane = tid & 63;
    const int n    = __builtin_amdgcn_readfirstlane(blockIdx.x * 4 + wid);
    const float c0 = 0.06681531047810609f;  // 1/sqrt(32*7)
    const float c1 = 0.06299407883487121f;  // 1/(sqrt(12*7)*sqrt(3))
    const float c2 = 0.05976143046671968f;  // 1/(sqrt(8*7)*sqrt(5))
    int code = 0, aA = 0, aB = 0;
    const float* Wb = W2_0; float norm = 0.f;
    const int j = lane;
    if (j < 16)      { code = 0; aA = 2 * j;   aB = aA + 1; Wb = W2_0; norm = c0; }
    else if (j < 34) { int g = (j - 16) / 6, r = (j - 16) % 6;
                       code = 1 + g; aA = 2 * r; aB = aA + 1; Wb = W2_1; norm = c1; }
    else if (j < 54) { int g = (j - 34) / 4, r = (j - 34) % 4;
                       code = 4 + g; aA = 2 * r; aB = aA + 1; Wb = W2_2; norm = c2; }
    float wA[NB], wB[NB];
    #pragma unroll
    for (int b = 0; b < NB; b++) {
        wA[b] = (j < 54) ? Wb[aA * NB + b] * norm : 0.f;
        wB[b] = (j < 54) ? Wb[aB * NB + b] * norm : 0.f;
    }
    const int jj = (j < 54) ? j : 0;

    int srcs[DEG];
    #pragma unroll
    for (int k = 0; k < DEG; k++)
        srcs[k] = __builtin_amdgcn_readfirstlane(edge_src[n * DEG + k]);

    // per-edge h factors, computed once by lanes 0..15 into the wave's table
    const int srcv = edge_src[n * DEG + (lane & 15)];
    const float pdx = pos[n * 3 + 0], pdy = pos[n * 3 + 1], pdz = pos[n * 3 + 2];
    if (lane < 16) {
        const float s3 = 1.7320508075688772f, s15 = 3.872983346207417f;
        const float s5h = 1.118033988749895f, s15h = 1.9364916731037085f;
        const float vx = pos[srcv * 3 + 0] - pdx;
        const float vy = pos[srcv * 3 + 1] - pdy;
        const float vz = pos[srcv * 3 + 2] - pdz;
        hb[wid][0][lane] = 1.0f;
        hb[wid][1][lane] = s3 * vx;
        hb[wid][2][lane] = s3 * vy;
        hb[wid][3][lane] = s3 * vz;
        hb[wid][4][lane] = s15 * vx * vy;
        hb[wid][5][lane] = s15 * vy * vz;
        hb[wid][6][lane] = s5h * (2.f * vz * vz - vx * vx - vy * vy);
        hb[wid][7][lane] = s15 * vx * vz;
        hb[wid][8][lane] = s15h * (vx * vx - vy * vy);
    }

    unsigned g[DEG];
    #pragma unroll
    for (int k = 0; k < DEG; k++)
        g[k] = *(const unsigned*)(sbuf + (size_t)srcs[k] * SROW + 2 * jj);

    const float* frow = &hb[wid][code][0];   // per-lane base; [k] is imm offset
    float accum = 0.f;
    #pragma unroll
    for (int k = 0; k < DEG; k++) {
        float ea[NB];
        const float* eap = edge_attr + ((size_t)n * DEG + k) * NB;   // uniform -> s_load
        #pragma unroll
        for (int b = 0; b < NB; b++) ea[b] = eap[b];
        const float f = frow[k];             // one ds_read_b32, broadcast by code
        float we0 = 0.f, we1 = 0.f;
        #pragma unroll
        for (int b = 0; b < NB; b++) { we0 += ea[b] * wA[b]; we1 += ea[b] * wB[b]; }
        accum += f * (bf_lo(g[k]) * we0 + bf_hi(g[k]) * we1);
    }
    #pragma unroll
    for (int off = 32; off >= 1; off >>= 1) accum += __shfl_xor(accum, off, 64);
    if (lane == 0) {
        atomicAdd(out + (n / 50), accum * 0.035355339059327376f); // 0.25/sqrt(50)
    }
}

extern "C" void kernel_launch(void* const* d_in, const int* in_sizes, int n_in,
                              void* d_out, int out_size, void* d_ws, size_t ws_size,
                              hipStream_t stream) {
    const float* pos  = (const float*)d_in[0];
    const float* x    = (const float*)d_in[1];
    const float* ea   = (const float*)d_in[2];
    const float* W1_0 = (const float*)d_in[3];
    const float* W1_1 = (const float*)d_in[4];
    const float* W1_2 = (const float*)d_in[5];
    const float* W2_0 = (const float*)d_in[6];
    const float* W2_1 = (const float*)d_in[7];
    const float* W2_2 = (const float*)d_in[8];
    const int*   esrc = (const int*)d_in[9];
    float* out = (float*)d_out;

    unsigned short* Wfrag = (unsigned short*)d_ws;                   // 28672 B
    unsigned short* sbuf  = (unsigned short*)((char*)d_ws + 32768);  // 12.8 MB

    hipLaunchKernelGGL(k0_zero, dim3(4), dim3(256), 0, stream, out);
    hipLaunchKernelGGL(k1_w, dim3((WFRAG_N * 8 + 255) / 256), dim3(256), 0, stream,
                       W1_0, W1_1, W1_2, Wfrag);
    hipLaunchKernelGGL(k2_s, dim3((N_ATOMS / NPW + 3) / 4), dim3(256), 0, stream,
                       pos, x, ea, esrc, Wfrag, sbuf);
    hipLaunchKernelGGL(k3_out, dim3(N_ATOMS / 4), dim3(256), 0, stream,
                       pos, ea, esrc, sbuf, W2_0, W2_1, W2_2, out);
}